// Round 1
// baseline (428.417 us; speedup 1.0000x reference)
//
#include <hip/hip_runtime.h>
#include <math.h>

#define N_TOK  16384
#define DIM    4096
#define NE     64
#define CAP    640
#define KC     32
#define TM     128
#define NTILES (N_TOK / TM)   // 128

// ws layout:
// [0,256):                     counts (64 int, zeroed per call)
// [256, 256+128K):             ws_idx   (int,   N*2)
// [256+128K, 256+256K):        ws_probs (float, N*2)
// [262400, ...):               partials (ks * N * 64 floats)

__global__ __launch_bounds__(256) void gemm_logits_kernel(
    const float* __restrict__ x, const float* __restrict__ W,
    float* __restrict__ partials, int ks) {
  const int tile  = blockIdx.x % NTILES;
  const int split = blockIdx.x / NTILES;
  const int klen  = DIM / ks;
  const int k0    = split * klen;
  const int t_base = tile * TM;

  __shared__ float xT[KC][TM + 4];  // stride 132 floats (528B, 16B aligned)
  __shared__ float wT[KC][NE + 4];  // stride 68  floats (272B, 16B aligned)

  const int tid = threadIdx.x;
  const int lr = tid >> 3;   // 0..31
  const int lc = tid & 7;    // 0..7
  const int tg = tid >> 3;   // token group: tokens tg*4 .. tg*4+3
  const int eg = tid & 7;    // expert group: experts eg*8 .. eg*8+7

  float acc[4][8];
#pragma unroll
  for (int i = 0; i < 4; ++i)
#pragma unroll
    for (int j = 0; j < 8; ++j) acc[i][j] = 0.f;

  for (int kc = 0; kc < klen; kc += KC) {
    const int kg = k0 + kc;
    // stage x tile (128 tokens x 32 k), transposed into LDS
#pragma unroll
    for (int i = 0; i < 4; ++i) {
      const int row = lr + i * 32;
      const float4 v = *(const float4*)(x + (size_t)(t_base + row) * DIM + kg + lc * 4);
      xT[lc * 4 + 0][row] = v.x; xT[lc * 4 + 1][row] = v.y;
      xT[lc * 4 + 2][row] = v.z; xT[lc * 4 + 3][row] = v.w;
    }
    // stage W tile (64 experts x 32 k), transposed into LDS
#pragma unroll
    for (int i = 0; i < 2; ++i) {
      const int row = lr + i * 32;
      const float4 v = *(const float4*)(W + (size_t)row * DIM + kg + lc * 4);
      wT[lc * 4 + 0][row] = v.x; wT[lc * 4 + 1][row] = v.y;
      wT[lc * 4 + 2][row] = v.z; wT[lc * 4 + 3][row] = v.w;
    }
    __syncthreads();
#pragma unroll
    for (int k = 0; k < KC; ++k) {
      const float4 xv = *(const float4*)&xT[k][tg * 4];
      const float4 w0 = *(const float4*)&wT[k][eg * 8];
      const float4 w1 = *(const float4*)&wT[k][eg * 8 + 4];
      const float xa[4] = {xv.x, xv.y, xv.z, xv.w};
      const float wa[8] = {w0.x, w0.y, w0.z, w0.w, w1.x, w1.y, w1.z, w1.w};
#pragma unroll
      for (int i = 0; i < 4; ++i)
#pragma unroll
        for (int j = 0; j < 8; ++j)
          acc[i][j] = fmaf(xa[i], wa[j], acc[i][j]);
    }
    __syncthreads();
  }

  float* outp = partials + (size_t)split * N_TOK * NE;
#pragma unroll
  for (int i = 0; i < 4; ++i) {
    const int t = t_base + tg * 4 + i;
    const float4 v0 = make_float4(acc[i][0], acc[i][1], acc[i][2], acc[i][3]);
    const float4 v1 = make_float4(acc[i][4], acc[i][5], acc[i][6], acc[i][7]);
    *(float4*)(outp + (size_t)t * NE + eg * 8)     = v0;
    *(float4*)(outp + (size_t)t * NE + eg * 8 + 4) = v1;
  }
}

__global__ __launch_bounds__(256) void route_kernel(
    const float* __restrict__ partials, int ks,
    float* __restrict__ out, int* __restrict__ ws_idx,
    float* __restrict__ ws_probs, int* __restrict__ counts) {
  __shared__ int cnt[NE];
  const int tid = threadIdx.x;
  if (tid < NE) cnt[tid] = 0;
  __syncthreads();
  const int t = blockIdx.x * 256 + tid;

  // top-2 with jax.lax.top_k tie semantics (lower index wins on equality)
  float b1 = -INFINITY, b2 = -INFINITY;
  int i1 = 0, i2 = 0;
  for (int e = 0; e < NE; e += 4) {
    float4 s = *(const float4*)(partials + (size_t)t * NE + e);
    for (int sp = 1; sp < ks; ++sp) {
      const float4 v = *(const float4*)(partials + (size_t)sp * N_TOK * NE + (size_t)t * NE + e);
      s.x += v.x; s.y += v.y; s.z += v.z; s.w += v.w;
    }
    const float vv[4] = {s.x, s.y, s.z, s.w};
#pragma unroll
    for (int j = 0; j < 4; ++j) {
      const float v = vv[j];
      const int idx = e + j;
      if (v > b1)      { b2 = b1; i2 = i1; b1 = v; i1 = idx; }
      else if (v > b2) { b2 = v; i2 = idx; }
    }
  }
  // softmax over the two kept scores (max-subtracted, like jax.nn.softmax)
  const float ed = expf(b2 - b1);
  const float p1 = 1.0f / (1.0f + ed);
  const float p2 = ed / (1.0f + ed);

  out[(size_t)t * 2]     = p1;
  out[(size_t)t * 2 + 1] = p2;
  out[(size_t)N_TOK * 2 + t * 2]     = (float)i1;  // indices stored as f32
  out[(size_t)N_TOK * 2 + t * 2 + 1] = (float)i2;
  ws_idx[t * 2] = i1;  ws_idx[t * 2 + 1] = i2;
  ws_probs[t * 2] = p1; ws_probs[t * 2 + 1] = p2;

  atomicAdd(&cnt[i1], 1);
  atomicAdd(&cnt[i2], 1);
  __syncthreads();
  if (tid < NE) atomicAdd(&counts[tid], cnt[tid]);
}

__global__ __launch_bounds__(256) void capacity_kernel(
    const int* __restrict__ counts, const int* __restrict__ ws_idx,
    const float* __restrict__ ws_probs, float* __restrict__ out) {
  const int e = blockIdx.x;
  const int cnt = counts[e];
  if (threadIdx.x == 0) out[(size_t)N_TOK * 4 + e] = (float)cnt;
  if (cnt <= CAP) return;  // cold path below: essentially never taken for this input
  for (int i = threadIdx.x; i < N_TOK * 2; i += 256) {
    if (ws_idx[i] != e) continue;
    const float p = ws_probs[i];
    const int tok = i >> 1;
    int rank = 0;
    for (int j = 0; j < N_TOK * 2; ++j) {
      if (ws_idx[j] != e) continue;
      const float q = ws_probs[j];
      if (q > p || (q == p && (j >> 1) < tok)) ++rank;
    }
    if (rank >= CAP) {
      out[i] = 0.0f;                                   // dropped prob
      out[(size_t)N_TOK * 2 + i] = 2147483648.0f;      // INT32_MAX as f32
    }
  }
}

extern "C" void kernel_launch(void* const* d_in, const int* in_sizes, int n_in,
                              void* d_out, int out_size, void* d_ws, size_t ws_size,
                              hipStream_t stream) {
  const float* x = (const float*)d_in[0];
  const float* W = (const float*)d_in[1];
  float* out = (float*)d_out;

  char* ws = (char*)d_ws;
  int*   counts   = (int*)ws;
  int*   ws_idx   = (int*)(ws + 256);
  float* ws_probs = (float*)(ws + 256 + (size_t)N_TOK * 2 * 4);
  float* partials = (float*)(ws + 262400);

  const size_t base = 262400;
  const size_t per  = (size_t)N_TOK * NE * 4;  // 4 MB per K-split partial
  int ks = 1;
  if (ws_size >= base + 4 * per)      ks = 4;
  else if (ws_size >= base + 2 * per) ks = 2;

  hipMemsetAsync(counts, 0, NE * sizeof(int), stream);
  gemm_logits_kernel<<<NTILES * ks, 256, 0, stream>>>(x, W, partials, ks);
  route_kernel<<<N_TOK / 256, 256, 0, stream>>>(partials, ks, out, ws_idx, ws_probs, counts);
  capacity_kernel<<<NE, 256, 0, stream>>>(counts, ws_idx, ws_probs, out);
}